// Round 1
// baseline (85.113 us; speedup 1.0000x reference)
//
#include <hip/hip_runtime.h>
#include <hip/hip_bf16.h>

// Problem constants
#define B_ 4
#define S_ 4096
#define H_ 1024
#define D_ 64
#define CHUNK 64
#define NCHUNK (S_ / CHUNK)  // 64 chunks per batch

typedef short bf16x8 __attribute__((ext_vector_type(8)));
typedef float f32x4 __attribute__((ext_vector_type(4)));

// fp32 -> bf16 bits, round-to-nearest-even
__device__ inline unsigned short f2bf(float f) {
    union { float f; unsigned u; } v; v.f = f;
    return (unsigned short)((v.u + 0x7fffu + ((v.u >> 16) & 1u)) >> 16);
}

__device__ inline bf16x8 cvt8(const float4& a, const float4& b) {
    bf16x8 r;
    r[0] = (short)f2bf(a.x); r[1] = (short)f2bf(a.y);
    r[2] = (short)f2bf(a.z); r[3] = (short)f2bf(a.w);
    r[4] = (short)f2bf(b.x); r[5] = (short)f2bf(b.y);
    r[6] = (short)f2bf(b.z); r[7] = (short)f2bf(b.w);
    return r;
}

// Kernel 0: transpose Wk, Wv ([H][D] fp32) -> WkT, WvT ([D][H] bf16)
__global__ void prep_w(const float* __restrict__ Wk, const float* __restrict__ Wv,
                       unsigned short* __restrict__ WkT, unsigned short* __restrict__ WvT) {
    int gid = blockIdx.x * 256 + threadIdx.x;  // gid = d*H + h, 0..65535
    int d = gid >> 10;
    int h = gid & (H_ - 1);
    WkT[gid] = f2bf(Wk[h * D_ + d]);
    WvT[gid] = f2bf(Wv[h * D_ + d]);
}

// Kernel A: per 64-row chunk, compute K_chunk = x@Wk, V_chunk = x@Wv (bf16 MFMA),
// then partial M = K_chunkᵀ V_chunk -> pM[block][64][64]
__global__ __launch_bounds__(256)
void kv_moment(const float* __restrict__ x, const unsigned short* __restrict__ WkT,
               const unsigned short* __restrict__ WvT, float* __restrict__ pM) {
    int b = blockIdx.x / NCHUNK;
    int c = blockIdx.x % NCHUNK;
    int s0 = c * CHUNK;
    int wv = threadIdx.x >> 6;       // wave 0..3, owns 16 rows
    int lane = threadIdx.x & 63;
    int r = lane & 15, kg = lane >> 4;

    __shared__ unsigned short Klds[64][64];
    __shared__ unsigned short Vlds[64][64];

    f32x4 accK[4] = {}, accV[4] = {};
    const float* xrow = x + ((size_t)b * S_ + s0 + wv * 16 + r) * H_;

    for (int h0 = 0; h0 < H_; h0 += 32) {
        int kb = h0 + kg * 8;
        float4 a0 = *(const float4*)(xrow + kb);
        float4 a1 = *(const float4*)(xrow + kb + 4);
        bf16x8 af = cvt8(a0, a1);
#pragma unroll
        for (int nt = 0; nt < 4; ++nt) {
            int col = nt * 16 + r;
            bf16x8 bk = *(const bf16x8*)(WkT + col * H_ + kb);
            bf16x8 bv = *(const bf16x8*)(WvT + col * H_ + kb);
            accK[nt] = __builtin_amdgcn_mfma_f32_16x16x32_bf16(af, bk, accK[nt], 0, 0, 0);
            accV[nt] = __builtin_amdgcn_mfma_f32_16x16x32_bf16(af, bv, accV[nt], 0, 0, 0);
        }
    }
    // D layout: row = wv*16 + kg*4 + i, col = nt*16 + r
#pragma unroll
    for (int nt = 0; nt < 4; ++nt)
#pragma unroll
        for (int i = 0; i < 4; ++i) {
            Klds[wv * 16 + kg * 4 + i][nt * 16 + r] = f2bf(accK[nt][i]);
            Vlds[wv * 16 + kg * 4 + i][nt * 16 + r] = f2bf(accV[nt][i]);
        }
    __syncthreads();

    // Stage 2: Mpart[e][d] = sum_s K[s][e]*V[s][d]; wave wv owns e-rows [wv*16, wv*16+16)
    f32x4 accM[4] = {};
#pragma unroll
    for (int ks = 0; ks < 2; ++ks) {
        bf16x8 af;
#pragma unroll
        for (int i = 0; i < 8; ++i)
            af[i] = (short)Klds[ks * 32 + kg * 8 + i][wv * 16 + r];
#pragma unroll
        for (int nt = 0; nt < 4; ++nt) {
            bf16x8 bfv;
#pragma unroll
            for (int i = 0; i < 8; ++i)
                bfv[i] = (short)Vlds[ks * 32 + kg * 8 + i][nt * 16 + r];
            accM[nt] = __builtin_amdgcn_mfma_f32_16x16x32_bf16(af, bfv, accM[nt], 0, 0, 0);
        }
    }
    float* outp = pM + (size_t)blockIdx.x * 4096;
#pragma unroll
    for (int nt = 0; nt < 4; ++nt)
#pragma unroll
        for (int i = 0; i < 4; ++i)
            outp[(wv * 16 + kg * 4 + i) * 64 + nt * 16 + r] = accM[nt][i];
}

// Kernel R: M[b][e][d] = sum over chunks of pM
__global__ void reduce_m(const float* __restrict__ pM, float* __restrict__ M) {
    int gid = blockIdx.x * 256 + threadIdx.x;  // 0..16383
    int b = gid >> 12;
    int idx = gid & 4095;
    const float* p = pM + (size_t)b * NCHUNK * 4096 + idx;
    float s = 0.f;
    for (int c = 0; c < NCHUNK; ++c) s += p[c * 4096];
    M[gid] = s;
}

// Kernel W: WpT[b][d][h] = bf16( (1/8) * sum_e Wq[h][e] * M[b][e][d] )
__global__ void make_wp(const float* __restrict__ Wq, const float* __restrict__ M,
                        unsigned short* __restrict__ WpT) {
    __shared__ float Mcol[64];
    int gid = blockIdx.x * 256 + threadIdx.x;  // b*65536 + d*1024 + h
    int h = gid & (H_ - 1);
    int d = (gid >> 10) & 63;
    int b = gid >> 16;
    if (threadIdx.x < 64) Mcol[threadIdx.x] = M[b * 4096 + threadIdx.x * 64 + d];
    __syncthreads();
    const float4* wq = (const float4*)(Wq + h * 64);
    float acc = 0.f;
#pragma unroll
    for (int e4 = 0; e4 < 16; ++e4) {
        float4 w = wq[e4];
        acc += w.x * Mcol[e4 * 4] + w.y * Mcol[e4 * 4 + 1] +
               w.z * Mcol[e4 * 4 + 2] + w.w * Mcol[e4 * 4 + 3];
    }
    WpT[gid] = f2bf(acc * 0.125f);
}

// Kernel B: out[b][s][d] = sum_h x[b][s][h] * Wp[h][d]   (Wp given transposed, bf16)
__global__ __launch_bounds__(256)
void final_proj(const float* __restrict__ x, const unsigned short* __restrict__ WpT,
                float* __restrict__ out) {
    int b = blockIdx.x / NCHUNK;
    int c = blockIdx.x % NCHUNK;
    int s0 = c * CHUNK;
    int wv = threadIdx.x >> 6, lane = threadIdx.x & 63;
    int r = lane & 15, kg = lane >> 4;
    const unsigned short* Wp = WpT + (size_t)b * (D_ * H_);

    f32x4 acc[4] = {};
    const float* xrow = x + ((size_t)b * S_ + s0 + wv * 16 + r) * H_;
    for (int h0 = 0; h0 < H_; h0 += 32) {
        int kb = h0 + kg * 8;
        float4 a0 = *(const float4*)(xrow + kb);
        float4 a1 = *(const float4*)(xrow + kb + 4);
        bf16x8 af = cvt8(a0, a1);
#pragma unroll
        for (int nt = 0; nt < 4; ++nt) {
            bf16x8 bw = *(const bf16x8*)(Wp + (nt * 16 + r) * H_ + kb);
            acc[nt] = __builtin_amdgcn_mfma_f32_16x16x32_bf16(af, bw, acc[nt], 0, 0, 0);
        }
    }
    float* orow = out + ((size_t)b * S_ + s0 + wv * 16) * 64;
#pragma unroll
    for (int nt = 0; nt < 4; ++nt)
#pragma unroll
        for (int i = 0; i < 4; ++i)
            orow[(kg * 4 + i) * 64 + nt * 16 + r] = acc[nt][i];
}

extern "C" void kernel_launch(void* const* d_in, const int* in_sizes, int n_in,
                              void* d_out, int out_size, void* d_ws, size_t ws_size,
                              hipStream_t stream) {
    const float* x  = (const float*)d_in[0];
    const float* Wk = (const float*)d_in[1];
    const float* Wq = (const float*)d_in[2];
    const float* Wv = (const float*)d_in[3];
    float* out = (float*)d_out;

    char* ws = (char*)d_ws;
    // layout: WkT[128K] | WvT[128K] | WpT[512K] | M[64K] | pM[4M]  (~4.9MB total)
    unsigned short* WkT = (unsigned short*)(ws);
    unsigned short* WvT = (unsigned short*)(ws + 131072);
    unsigned short* WpT = (unsigned short*)(ws + 262144);
    float* M  = (float*)(ws + 786432);
    float* pM = (float*)(ws + 851968);

    prep_w<<<256, 256, 0, stream>>>(Wk, Wv, WkT, WvT);
    kv_moment<<<B_ * NCHUNK, 256, 0, stream>>>(x, WkT, WvT, pM);
    reduce_m<<<64, 256, 0, stream>>>(pM, M);
    make_wp<<<1024, 256, 0, stream>>>(Wq, M, WpT);
    final_proj<<<B_ * NCHUNK, 256, 0, stream>>>(x, WpT, out);
}